// Round 3
// baseline (247.240 us; speedup 1.0000x reference)
//
#include <hip/hip_runtime.h>
#include <math.h>

// x[N,D] f32, w[D,1] f32. a=sigmoid(x@w) in (0,1) (bimodal ~{0,1} since
// std(x.w)=||w||~32), b=cumsum(a), idx=floor(b) non-decreasing, steps in {0,1}.
// Column i contributes mainv[i] at row idx[i], crossv[i] at row idx[i]-1 (on
// crossings). Row r's columns = [rowptr[r], rowptr[r+1]).
//
// Kernel 1 (fused): per-wave row dots + sigmoid -> a[], then last-block-done
// (atomic counter + device fences) runs the 256-thread f64 scan producing
// mainv/crossv/rowptr. Kernel 2: two output rows per block, sharing the
// crossing column's x row; negligible weights (<1e-7) skip their x-row read.

__global__ __launch_bounds__(256) void dot_scan_kernel(
    const float* __restrict__ x, const float* __restrict__ w,
    float* __restrict__ a, float* __restrict__ mainv, float* __restrict__ crossv,
    int* __restrict__ rowptr, int* __restrict__ counter, int N, int D) {
  __shared__ float sa[8192];
  __shared__ double wtot[4];
  __shared__ double woff[4];
  __shared__ int lastflag;
  int t = threadIdx.x;
  int lane = t & 63;
  int wave = t >> 6;

  // ---- part 1: one row dot per wave (4 rows per block) ----
  int row = blockIdx.x * 4 + wave;
  {
    const float4* xr = reinterpret_cast<const float4*>(x + (size_t)row * D);
    const float4* w4 = reinterpret_cast<const float4*>(w);
    float acc = 0.f;
    int nv = D >> 2;  // 256
    for (int j = lane; j < nv; j += 64) {
      float4 xv = xr[j];
      float4 wv = w4[j];
      acc = fmaf(xv.x, wv.x, acc);
      acc = fmaf(xv.y, wv.y, acc);
      acc = fmaf(xv.z, wv.z, acc);
      acc = fmaf(xv.w, wv.w, acc);
    }
#pragma unroll
    for (int off = 32; off > 0; off >>= 1) acc += __shfl_down(acc, off, 64);
    if (lane == 0) a[row] = 1.0f / (1.0f + expf(-acc));
  }
  // default-init this block's rowptr entries (scan scatters crossings later)
  if (t < 4) rowptr[blockIdx.x * 4 + t] = N;
  if (blockIdx.x == 0 && t == 4) rowptr[N] = N;

  // ---- last-block handoff ----
  __threadfence();  // release a[] + rowptr defaults
  if (t == 0) lastflag = (atomicAdd(counter, 1) == (int)gridDim.x - 1);
  __syncthreads();
  if (!lastflag) return;
  __threadfence();  // acquire

  // ---- part 2: 256-thread scan over N elements ----
  for (int k = t; k < N; k += 256) sa[k] = a[k];
  __syncthreads();
  const int per = N / 256;  // 32
  int base = t * per;
  double run = 0.0;
  for (int j = 0; j < per; ++j) run += (double)sa[base + j];
  // inclusive scan of per-thread totals: wave shuffle + cross-wave via LDS
  double v = run;
  for (int off = 1; off < 64; off <<= 1) {
    double n = __shfl_up(v, off, 64);
    if (lane >= off) v += n;
  }
  if (lane == 63) wtot[wave] = v;
  __syncthreads();
  if (t == 0) {
    double s = 0.0;
    for (int q = 0; q < 4; ++q) { woff[q] = s; s += wtot[q]; }
  }
  __syncthreads();
  double prevbd = woff[wave] + (v - run);  // exclusive prefix before chunk
  if (t == 0) rowptr[0] = 0;               // row 0 always starts at column 0
  for (int j = 0; j < per; ++j) {
    int i = base + j;
    double bd = prevbd + (double)sa[i];
    float bf = (float)bd;
    float pf = (float)prevbd;
    int k = (int)floorf(bf);
    int kp = (int)floorf(pf);
    float ai = sa[i];
    float frac = bf - (float)k;
    bool same = (k == kp);
    mainv[i] = same ? ai : frac;
    crossv[i] = same ? 0.f : (ai - frac);
    if (!same) rowptr[k] = i;  // unique crossing per row k>=1
    prevbd = bd;
  }
}

// Two output rows per block; crossing column s1's x row is shared by the pair.
__global__ __launch_bounds__(256) void out_kernel(
    const float* __restrict__ x, const float* __restrict__ mainv,
    const float* __restrict__ crossv, const int* __restrict__ rowptr,
    float* __restrict__ out, int N, int D) {
  int r0 = blockIdx.x * 2;
  int s0 = rowptr[r0];
  int s1 = rowptr[r0 + 1];
  int s2 = rowptr[r0 + 2];

  int c = threadIdx.x << 2;  // 256 threads * 4 floats = D
  float4 acc0 = make_float4(0.f, 0.f, 0.f, 0.f);
  float4 acc1 = make_float4(0.f, 0.f, 0.f, 0.f);

  // row r0 main columns [s0, s1)
  for (int i = s0; i < s1; ++i) {
    float wgt = mainv[i];
    if (wgt < 1e-7f) continue;  // a_i ~ 0: negligible, skip the 4KB row read
    float4 xv = *reinterpret_cast<const float4*>(x + (size_t)i * D + c);
    acc0.x = fmaf(wgt, xv.x, acc0.x);
    acc0.y = fmaf(wgt, xv.y, acc0.y);
    acc0.z = fmaf(wgt, xv.z, acc0.z);
    acc0.w = fmaf(wgt, xv.w, acc0.w);
  }
  // shared crossing column s1: cross into r0, main into r1
  if (s1 < N) {
    float wc = crossv[s1];
    float wm = mainv[s1];
    float4 xv = *reinterpret_cast<const float4*>(x + (size_t)s1 * D + c);
    acc0.x = fmaf(wc, xv.x, acc0.x);
    acc0.y = fmaf(wc, xv.y, acc0.y);
    acc0.z = fmaf(wc, xv.z, acc0.z);
    acc0.w = fmaf(wc, xv.w, acc0.w);
    acc1.x = fmaf(wm, xv.x, acc1.x);
    acc1.y = fmaf(wm, xv.y, acc1.y);
    acc1.z = fmaf(wm, xv.z, acc1.z);
    acc1.w = fmaf(wm, xv.w, acc1.w);
  }
  // row r1 remaining main columns (s1, s2)
  for (int i = s1 + 1; i < s2; ++i) {
    float wgt = mainv[i];
    if (wgt < 1e-7f) continue;
    float4 xv = *reinterpret_cast<const float4*>(x + (size_t)i * D + c);
    acc1.x = fmaf(wgt, xv.x, acc1.x);
    acc1.y = fmaf(wgt, xv.y, acc1.y);
    acc1.z = fmaf(wgt, xv.z, acc1.z);
    acc1.w = fmaf(wgt, xv.w, acc1.w);
  }
  // row r1 cross column s2
  if (s2 < N) {
    float wc = crossv[s2];
    float4 xv = *reinterpret_cast<const float4*>(x + (size_t)s2 * D + c);
    acc1.x = fmaf(wc, xv.x, acc1.x);
    acc1.y = fmaf(wc, xv.y, acc1.y);
    acc1.z = fmaf(wc, xv.z, acc1.z);
    acc1.w = fmaf(wc, xv.w, acc1.w);
  }
  *reinterpret_cast<float4*>(out + (size_t)r0 * D + c) = acc0;
  *reinterpret_cast<float4*>(out + (size_t)(r0 + 1) * D + c) = acc1;
}

extern "C" void kernel_launch(void* const* d_in, const int* in_sizes, int n_in,
                              void* d_out, int out_size, void* d_ws, size_t ws_size,
                              hipStream_t stream) {
  const float* x = (const float*)d_in[0];
  const float* w = (const float*)d_in[1];
  float* out = (float*)d_out;
  int D = in_sizes[1];      // 1024
  int N = in_sizes[0] / D;  // 8192

  float* a = (float*)d_ws;
  float* mainv = a + N;
  float* crossv = mainv + N;
  int* rowptr = (int*)(crossv + N);    // N+1 entries
  int* counter = rowptr + (N + 1);

  hipMemsetAsync(counter, 0, sizeof(int), stream);  // capturable memset node

  // Kernel 1: fused dot+sigmoid (4 rows/block) + last-block scan
  hipLaunchKernelGGL(dot_scan_kernel, dim3(N / 4), dim3(256), 0, stream,
                     x, w, a, mainv, crossv, rowptr, counter, N, D);

  // Kernel 2: two output rows per block
  hipLaunchKernelGGL(out_kernel, dim3(N / 2), dim3(256), 0, stream,
                     x, mainv, crossv, rowptr, out, N, D);
}

// Round 4
// 107.378 us; speedup vs baseline: 2.3025x; 2.3025x over previous
//
#include <hip/hip_runtime.h>
#include <math.h>

// x[N,D] f32, w[D,1] f32. a=sigmoid(x@w) in (0,1), b=cumsum(a), idx=floor(b)
// non-decreasing with steps in {0,1} (a<1), bins never skip. Column i
// contributes mainv[i] to row idx[i] and crossv[i] to row idx[i]-1 (crossings
// only). Row r's columns = [rowptr[r], rowptr[r+1]).
//
// K1: per-wave row dot + sigmoid. K2: single-block f64 scan -> mainv/crossv/
// idxv/rowptr. K3: R=8 rows per block, streams the block's column range once
// (LDS-cached weights, shared crossing reads, eps-skip of negligible columns).

__global__ void dot_sigmoid_kernel(const float* __restrict__ x,
                                   const float* __restrict__ w,
                                   float* __restrict__ a, int N, int D) {
  int lane = threadIdx.x & 63;
  int wave = threadIdx.x >> 6;
  int row = blockIdx.x * (blockDim.x >> 6) + wave;
  if (row >= N) return;
  const float4* xr = reinterpret_cast<const float4*>(x + (size_t)row * D);
  const float4* w4 = reinterpret_cast<const float4*>(w);
  float acc = 0.f;
  int nv = D >> 2;  // 256
  for (int j = lane; j < nv; j += 64) {
    float4 xv = xr[j];
    float4 wv = w4[j];
    acc = fmaf(xv.x, wv.x, acc);
    acc = fmaf(xv.y, wv.y, acc);
    acc = fmaf(xv.z, wv.z, acc);
    acc = fmaf(xv.w, wv.w, acc);
  }
#pragma unroll
  for (int off = 32; off > 0; off >>= 1) acc += __shfl_down(acc, off, 64);
  if (lane == 0) a[row] = 1.0f / (1.0f + expf(-acc));
}

// Single-block scan: 1024 threads x 8 elements, f64 running sum (tighter than
// the reference's f32 cumsum). Emits mainv/crossv/idxv and rowptr[r] = first
// column of row r (N if row empty).
__global__ __launch_bounds__(1024) void scan_kernel(const float* __restrict__ a,
                                                    float* __restrict__ mainv,
                                                    float* __restrict__ crossv,
                                                    int* __restrict__ idxv,
                                                    int* __restrict__ rowptr, int N) {
  __shared__ float sa[8192];
  __shared__ double wtot[16];
  __shared__ double woff[16];
  int t = threadIdx.x;
  for (int k = t; k < N; k += 1024) sa[k] = a[k];     // coalesced stage
  for (int k = t; k <= N; k += 1024) rowptr[k] = N;   // defaults (pre-barrier)
  if (t == 0) rowptr[0] = 0;
  __syncthreads();

  const int per = 8;  // N/1024
  int base = t * per;
  double loc[8];
  double run = 0.0;
#pragma unroll
  for (int j = 0; j < 8; ++j) {
    run += (double)sa[base + j];
    loc[j] = run;
  }
  double v = run;
  int lane = t & 63;
  int wid = t >> 6;  // 16 waves
  for (int off = 1; off < 64; off <<= 1) {
    double n = __shfl_up(v, off, 64);
    if (lane >= off) v += n;
  }
  if (lane == 63) wtot[wid] = v;
  __syncthreads();
  if (t == 0) {
    double s = 0.0;
    for (int q = 0; q < 16; ++q) { woff[q] = s; s += wtot[q]; }
  }
  __syncthreads();
  double pre = woff[wid] + (v - run);  // exclusive prefix before this chunk
  double prevbd = pre;
#pragma unroll
  for (int j = 0; j < 8; ++j) {
    int i = base + j;
    double bd = pre + loc[j];
    float bf = (float)bd;
    float pf = (float)prevbd;
    int k = (int)floorf(bf);
    int kp = (int)floorf(pf);  // i==0 -> pre==0 -> kp==0, matches prev[0]=0
    float ai = sa[i];
    float frac = bf - (float)k;
    bool same = (k == kp);
    mainv[i] = same ? ai : frac;
    crossv[i] = same ? 0.f : (ai - frac);
    idxv[i] = k;
    if (!same) rowptr[k] = i;  // unique crossing per row k>=1
    prevbd = bd;
  }
}

// R rows per block; stream columns [rowptr[r0], rowptr[r0+R]] once, flushing
// each row as the running bin advances. Weights cached in LDS.
constexpr int R = 8;
constexpr int CAP = 1024;

__global__ __launch_bounds__(256) void out_kernel(
    const float* __restrict__ x, const float* __restrict__ mainv,
    const float* __restrict__ crossv, const int* __restrict__ idxv,
    const int* __restrict__ rowptr, float* __restrict__ out, int N, int D) {
  __shared__ float sm[CAP];
  __shared__ float sc[CAP];
  __shared__ int sk[CAP];
  int r0 = blockIdx.x * R;
  int s_begin = rowptr[r0];
  int s_endp = rowptr[r0 + R];              // first column of row r0+R (or N)
  int len = s_endp - s_begin;               // columns owned by this block
  int total = len + (s_endp < N ? 1 : 0);   // + boundary crossing column
  int t = threadIdx.x;
  bool use_lds = (s_begin < N) && (total <= CAP);
  if (use_lds) {
    for (int j = t; j < total; j += 256) {
      sm[j] = mainv[s_begin + j];
      sc[j] = crossv[s_begin + j];
      sk[j] = idxv[s_begin + j];
    }
    __syncthreads();
  }
  int c = t << 2;  // 256 threads * 4 floats = D
  float4 acc = make_float4(0.f, 0.f, 0.f, 0.f);
  int cur = r0;
  for (int j = 0; j < len; ++j) {
    int i = s_begin + j;
    float wm, wc;
    int k;
    if (use_lds) { wm = sm[j]; wc = sc[j]; k = sk[j]; }
    else         { wm = mainv[i]; wc = crossv[i]; k = idxv[i]; }
    if (k > cur) {
      while (cur < k - 1) {  // defensive: bins never skip, loop body dead
        *reinterpret_cast<float4*>(out + (size_t)cur * D + c) = acc;
        acc = make_float4(0.f, 0.f, 0.f, 0.f);
        ++cur;
      }
      // crossing column: cross -> row cur (==k-1), main -> row k; read x once
      float4 xv = *reinterpret_cast<const float4*>(x + (size_t)i * D + c);
      acc.x = fmaf(wc, xv.x, acc.x);
      acc.y = fmaf(wc, xv.y, acc.y);
      acc.z = fmaf(wc, xv.z, acc.z);
      acc.w = fmaf(wc, xv.w, acc.w);
      *reinterpret_cast<float4*>(out + (size_t)cur * D + c) = acc;
      cur = k;
      acc.x = wm * xv.x;
      acc.y = wm * xv.y;
      acc.z = wm * xv.z;
      acc.w = wm * xv.w;
    } else if (wm >= 1e-7f) {  // same-bin column; skip negligible reads
      float4 xv = *reinterpret_cast<const float4*>(x + (size_t)i * D + c);
      acc.x = fmaf(wm, xv.x, acc.x);
      acc.y = fmaf(wm, xv.y, acc.y);
      acc.z = fmaf(wm, xv.z, acc.z);
      acc.w = fmaf(wm, xv.w, acc.w);
    }
  }
  if (s_endp < N) {  // boundary column's cross completes row r0+R-1 (== cur)
    float wc = use_lds ? sc[len] : crossv[s_endp];
    float4 xv = *reinterpret_cast<const float4*>(x + (size_t)s_endp * D + c);
    acc.x = fmaf(wc, xv.x, acc.x);
    acc.y = fmaf(wc, xv.y, acc.y);
    acc.z = fmaf(wc, xv.z, acc.z);
    acc.w = fmaf(wc, xv.w, acc.w);
  }
  *reinterpret_cast<float4*>(out + (size_t)cur * D + c) = acc;
  float4 z = make_float4(0.f, 0.f, 0.f, 0.f);
  for (int r = cur + 1; r < r0 + R; ++r)  // empty tail rows -> zeros
    *reinterpret_cast<float4*>(out + (size_t)r * D + c) = z;
}

extern "C" void kernel_launch(void* const* d_in, const int* in_sizes, int n_in,
                              void* d_out, int out_size, void* d_ws, size_t ws_size,
                              hipStream_t stream) {
  const float* x = (const float*)d_in[0];
  const float* w = (const float*)d_in[1];
  float* out = (float*)d_out;
  int D = in_sizes[1];      // 1024
  int N = in_sizes[0] / D;  // 8192

  float* a = (float*)d_ws;
  float* mainv = a + N;
  float* crossv = mainv + N;
  int* idxv = (int*)(crossv + N);
  int* rowptr = idxv + N;  // N+1 entries

  hipLaunchKernelGGL(dot_sigmoid_kernel, dim3(N / 4), dim3(256), 0, stream,
                     x, w, a, N, D);
  hipLaunchKernelGGL(scan_kernel, dim3(1), dim3(1024), 0, stream,
                     a, mainv, crossv, idxv, rowptr, N);
  hipLaunchKernelGGL(out_kernel, dim3(N / R), dim3(256), 0, stream,
                     x, mainv, crossv, idxv, rowptr, out, N, D);
}

// Round 5
// 100.928 us; speedup vs baseline: 2.4497x; 1.0639x over previous
//
#include <hip/hip_runtime.h>
#include <math.h>

// x[N,D] f32, w[D,1] f32. a=sigmoid(x@w) in (0,1), b=cumsum(a), idx=floor(b)
// non-decreasing with steps in {0,1} (a<1), interior bins never skip. Column i
// contributes mainv[i] to row idx[i] and crossv[i] to row idx[i]-1 (crossings).
// Row r's columns = [rowptr[r], rowptr[r+1]).
//
// K1: 16 row-dots per 1024-thread block + sigmoid -> a[]; per-256-chunk f64
//     atomic partial sums; rowptr defaults.
// K2: 32 blocks x 256 threads: serial exclusive chunk prefix (32 f64 adds) +
//     intra-block f64 shuffle scan -> mainv/crossv/idxv + rowptr scatters.
// K3: R=8 rows per block, streams its column range once (LDS weights, shared
//     crossing reads, eps-skip of negligible columns).

__global__ __launch_bounds__(1024) void dot_sigmoid_kernel(
    const float* __restrict__ x, const float* __restrict__ w,
    float* __restrict__ a, double* __restrict__ chunksum,
    int* __restrict__ rowptr, int N, int D) {
  __shared__ float was[16];
  int t = threadIdx.x;
  int lane = t & 63;
  int wave = t >> 6;
  int row = blockIdx.x * 16 + wave;
  const float4* xr = reinterpret_cast<const float4*>(x + (size_t)row * D);
  const float4* w4 = reinterpret_cast<const float4*>(w);
  float acc = 0.f;
  int nv = D >> 2;  // 256
  for (int j = lane; j < nv; j += 64) {
    float4 xv = xr[j];
    float4 wv = w4[j];
    acc = fmaf(xv.x, wv.x, acc);
    acc = fmaf(xv.y, wv.y, acc);
    acc = fmaf(xv.z, wv.z, acc);
    acc = fmaf(xv.w, wv.w, acc);
  }
#pragma unroll
  for (int off = 32; off > 0; off >>= 1) acc += __shfl_down(acc, off, 64);
  if (lane == 0) {
    float av = 1.0f / (1.0f + expf(-acc));
    a[row] = av;
    was[wave] = av;
  }
  int gtid = blockIdx.x * 1024 + t;
  if (gtid <= N) rowptr[gtid] = N;  // defaults; k2 overwrites crossings later
  __syncthreads();
  if (t == 0) {
    double s = 0.0;
    for (int q = 0; q < 16; ++q) s += (double)was[q];
    atomicAdd(&chunksum[blockIdx.x >> 4], s);  // 16 blocks per 256-row chunk
  }
}

// 32 blocks x 256 threads; block b owns columns [256b, 256b+256).
__global__ __launch_bounds__(256) void scan_emit_kernel(
    const float* __restrict__ a, const double* __restrict__ chunksum,
    float* __restrict__ mainv, float* __restrict__ crossv,
    int* __restrict__ idxv, int* __restrict__ rowptr, int N) {
  __shared__ double spre_s;
  __shared__ double wtot[4];
  int b = blockIdx.x;
  int t = threadIdx.x;
  int i = b * 256 + t;
  int lane = t & 63;
  int wid = t >> 6;
  float ai = a[i];
  if (t == 0) {
    double s = 0.0;
    for (int q = 0; q < b; ++q) s += chunksum[q];
    spre_s = s;
    if (b == 0) rowptr[0] = 0;  // row 0 starts at column 0; never scattered
  }
  // f64 inclusive scan within wave
  double v = (double)ai;
  for (int off = 1; off < 64; off <<= 1) {
    double n = __shfl_up(v, off, 64);
    if (lane >= off) v += n;
  }
  if (lane == 63) wtot[wid] = v;
  __syncthreads();
  double pre = spre_s;
  for (int q = 0; q < wid; ++q) pre += wtot[q];
  double bd = pre + v;             // inclusive b_i
  double prevbd = bd - (double)ai; // exclusive prefix
  float bf = (float)bd;
  float pf = (float)prevbd;
  int k = (int)floorf(bf);
  int kp = (int)floorf(pf);
  float frac = bf - (float)k;
  bool same = (k == kp);
  mainv[i] = same ? ai : frac;
  crossv[i] = same ? 0.f : (ai - frac);
  idxv[i] = k;
  if (!same) rowptr[k] = i;  // unique crossing per row k>=1
}

// R rows per block; stream columns [rowptr[r0], rowptr[r0+R]] once, flushing
// each row as the running bin advances. Weights cached in LDS.
constexpr int R = 8;
constexpr int CAP = 1024;

__global__ __launch_bounds__(256) void out_kernel(
    const float* __restrict__ x, const float* __restrict__ mainv,
    const float* __restrict__ crossv, const int* __restrict__ idxv,
    const int* __restrict__ rowptr, float* __restrict__ out, int N, int D) {
  __shared__ float sm[CAP];
  __shared__ float sc[CAP];
  __shared__ int sk[CAP];
  int r0 = blockIdx.x * R;
  int s_begin = rowptr[r0];
  int s_endp = rowptr[r0 + R];              // first column of row r0+R (or N)
  int len = s_endp - s_begin;               // columns owned by this block
  int total = len + (s_endp < N ? 1 : 0);   // + boundary crossing column
  int t = threadIdx.x;
  bool use_lds = (s_begin < N) && (total <= CAP);
  if (use_lds) {
    for (int j = t; j < total; j += 256) {
      sm[j] = mainv[s_begin + j];
      sc[j] = crossv[s_begin + j];
      sk[j] = idxv[s_begin + j];
    }
    __syncthreads();
  }
  int c = t << 2;  // 256 threads * 4 floats = D
  float4 acc = make_float4(0.f, 0.f, 0.f, 0.f);
  int cur = r0;
  for (int j = 0; j < len; ++j) {
    int i = s_begin + j;
    float wm, wc;
    int k;
    if (use_lds) { wm = sm[j]; wc = sc[j]; k = sk[j]; }
    else         { wm = mainv[i]; wc = crossv[i]; k = idxv[i]; }
    if (k > cur) {
      while (cur < k - 1) {  // defensive: interior bins never skip
        *reinterpret_cast<float4*>(out + (size_t)cur * D + c) = acc;
        acc = make_float4(0.f, 0.f, 0.f, 0.f);
        ++cur;
      }
      // crossing column: cross -> row cur (==k-1), main -> row k; read x once
      float4 xv = *reinterpret_cast<const float4*>(x + (size_t)i * D + c);
      acc.x = fmaf(wc, xv.x, acc.x);
      acc.y = fmaf(wc, xv.y, acc.y);
      acc.z = fmaf(wc, xv.z, acc.z);
      acc.w = fmaf(wc, xv.w, acc.w);
      *reinterpret_cast<float4*>(out + (size_t)cur * D + c) = acc;
      cur = k;
      acc.x = wm * xv.x;
      acc.y = wm * xv.y;
      acc.z = wm * xv.z;
      acc.w = wm * xv.w;
    } else if (wm >= 1e-7f) {  // same-bin column; skip negligible reads
      float4 xv = *reinterpret_cast<const float4*>(x + (size_t)i * D + c);
      acc.x = fmaf(wm, xv.x, acc.x);
      acc.y = fmaf(wm, xv.y, acc.y);
      acc.z = fmaf(wm, xv.z, acc.z);
      acc.w = fmaf(wm, xv.w, acc.w);
    }
  }
  if (s_endp < N) {  // boundary column's cross completes row r0+R-1 (== cur)
    float wc = use_lds ? sc[len] : crossv[s_endp];
    float4 xv = *reinterpret_cast<const float4*>(x + (size_t)s_endp * D + c);
    acc.x = fmaf(wc, xv.x, acc.x);
    acc.y = fmaf(wc, xv.y, acc.y);
    acc.z = fmaf(wc, xv.z, acc.z);
    acc.w = fmaf(wc, xv.w, acc.w);
  }
  *reinterpret_cast<float4*>(out + (size_t)cur * D + c) = acc;
  float4 z = make_float4(0.f, 0.f, 0.f, 0.f);
  for (int r = cur + 1; r < r0 + R; ++r)  // empty tail rows -> zeros
    *reinterpret_cast<float4*>(out + (size_t)r * D + c) = z;
}

extern "C" void kernel_launch(void* const* d_in, const int* in_sizes, int n_in,
                              void* d_out, int out_size, void* d_ws, size_t ws_size,
                              hipStream_t stream) {
  const float* x = (const float*)d_in[0];
  const float* w = (const float*)d_in[1];
  float* out = (float*)d_out;
  int D = in_sizes[1];      // 1024
  int N = in_sizes[0] / D;  // 8192

  float* a = (float*)d_ws;
  float* mainv = a + N;
  float* crossv = mainv + N;
  int* idxv = (int*)(crossv + N);
  int* rowptr = idxv + N;                      // N+1 entries
  double* chunksum = (double*)(((uintptr_t)(rowptr + N + 1) + 15) & ~15ull);

  hipMemsetAsync(chunksum, 0, 32 * sizeof(double), stream);  // capturable

  hipLaunchKernelGGL(dot_sigmoid_kernel, dim3(N / 16), dim3(1024), 0, stream,
                     x, w, a, chunksum, rowptr, N, D);
  hipLaunchKernelGGL(scan_emit_kernel, dim3(N / 256), dim3(256), 0, stream,
                     a, chunksum, mainv, crossv, idxv, rowptr, N);
  hipLaunchKernelGGL(out_kernel, dim3(N / R), dim3(256), 0, stream,
                     x, mainv, crossv, idxv, rowptr, out, N, D);
}

// Round 6
// 92.248 us; speedup vs baseline: 2.6802x; 1.0941x over previous
//
#include <hip/hip_runtime.h>
#include <math.h>

// x[N,D] f32, w[D,1] f32. a=sigmoid(x@w) in (0,1), b=cumsum(a), idx=floor(b)
// non-decreasing with steps in {0,1}; bins never skip (a<1 strictly, and the
// f32 rounding window at b~4096 is +-ulp/2 ~ 2.4e-4 so floor can't jump 2).
// Column i contributes mainv[i] to row idx[i], crossv[i] to row idx[i]-1.
// Row r's main columns = [rowptr[r], rowptr[r+1]); its cross column is
// rowptr[r+1] (first column of row r+1), if < N.
//
// K1: 4 row-dots per 256-thread block -> a[]; per-block f64 partial sums
//     (no atomics, no memset: every slot written each call); rowptr defaults.
// K2: 32 blocks x 256 threads: two-level parallel f64 scan (256 group sums of
//     32 columns -> wave scan; within-wave scan of a) -> mainv/crossv +
//     rowptr crossing scatters.
// K3: ONE row per block (8192 blocks, ~4096 working = 16/CU): read weights,
//     accumulate non-negligible columns, write the row. No idxv needed.

__global__ __launch_bounds__(256) void dot_sigmoid_kernel(
    const float* __restrict__ x, const float* __restrict__ w,
    float* __restrict__ a, double* __restrict__ blocksum,
    int* __restrict__ rowptr, int N, int D) {
  __shared__ float was[4];
  int t = threadIdx.x;
  int lane = t & 63;
  int wave = t >> 6;
  int row = blockIdx.x * 4 + wave;
  const float4* xr = reinterpret_cast<const float4*>(x + (size_t)row * D);
  const float4* w4 = reinterpret_cast<const float4*>(w);
  float acc = 0.f;
  int nv = D >> 2;  // 256
  for (int j = lane; j < nv; j += 64) {
    float4 xv = xr[j];
    float4 wv = w4[j];
    acc = fmaf(xv.x, wv.x, acc);
    acc = fmaf(xv.y, wv.y, acc);
    acc = fmaf(xv.z, wv.z, acc);
    acc = fmaf(xv.w, wv.w, acc);
  }
#pragma unroll
  for (int off = 32; off > 0; off >>= 1) acc += __shfl_down(acc, off, 64);
  if (lane == 0) {
    float av = 1.0f / (1.0f + expf(-acc));
    a[row] = av;
    was[wave] = av;
  }
  int gtid = blockIdx.x * 256 + t;
  if (gtid <= N) rowptr[gtid] = N;  // defaults; k2 scatters crossings later
  __syncthreads();
  if (t == 0)
    blocksum[blockIdx.x] =
        (double)was[0] + (double)was[1] + (double)was[2] + (double)was[3];
}

// 32 blocks x 256 threads; block b owns columns [256b, 256b+256).
__global__ __launch_bounds__(256) void scan_emit_kernel(
    const float* __restrict__ a, const double* __restrict__ blocksum,
    float* __restrict__ mainv, float* __restrict__ crossv,
    int* __restrict__ rowptr, int N) {
  __shared__ double sg[256];  // exclusive group prefixes (group = 32 columns)
  __shared__ double wtot[4];
  int b = blockIdx.x;
  int t = threadIdx.x;
  int lane = t & 63;
  int wid = t >> 6;

  // group t = blocksums [8t, 8t+8) = columns [32t, 32t+32)
  double g = 0.0;
#pragma unroll
  for (int j = 0; j < 8; ++j) g += blocksum[8 * t + j];
  double vg = g;  // inclusive wave scan of group sums
  for (int off = 1; off < 64; off <<= 1) {
    double n = __shfl_up(vg, off, 64);
    if (lane >= off) vg += n;
  }
  if (lane == 63) wtot[wid] = vg;
  __syncthreads();
  double wb = 0.0;
  for (int q = 0; q < wid; ++q) wb += wtot[q];
  sg[t] = wb + vg - g;  // exclusive prefix of group t over all N columns
  __syncthreads();

  // per-column: exclusive prefix = sg[group] + within-group f64 scan of a
  int i = b * 256 + t;
  float ai = a[i];
  double va = (double)ai;  // inclusive wave scan of a
  for (int off = 1; off < 64; off <<= 1) {
    double n = __shfl_up(va, off, 64);
    if (lane >= off) va += n;
  }
  double E = va - (double)ai;          // exclusive prefix within wave
  int g0 = lane & ~31;                 // group start lane (0 or 32)
  double Eg0 = __shfl(E, g0, 64);
  int gg = 8 * b + (t >> 5);           // global group index of column i
  double prevbd = sg[gg] + (E - Eg0);
  double bd = prevbd + (double)ai;
  float bf = (float)bd;
  float pf = (float)prevbd;
  int k = (int)floorf(bf);
  int kp = (int)floorf(pf);
  float frac = bf - (float)k;
  bool same = (k == kp);
  mainv[i] = same ? ai : frac;
  crossv[i] = same ? 0.f : (ai - frac);
  if (!same) rowptr[k] = i;  // crossings have k>=1; unique per row
  if (b == 0 && t == 0) rowptr[0] = 0;  // row 0 starts at column 0
}

// One row per block. ~4096 working blocks (16/CU) hide the x-row load latency.
__global__ __launch_bounds__(256) void out_kernel(
    const float* __restrict__ x, const float* __restrict__ mainv,
    const float* __restrict__ crossv, const int* __restrict__ rowptr,
    float* __restrict__ out, int N, int D) {
  int r = blockIdx.x;
  int s0 = rowptr[r];
  int s1 = rowptr[r + 1];
  int c = threadIdx.x << 2;  // 256 threads * 4 floats = D
  float4 acc = make_float4(0.f, 0.f, 0.f, 0.f);
  for (int i = s0; i < s1; ++i) {  // main columns of row r (empty row: s0==s1)
    float wm = mainv[i];
    if (wm >= 1e-7f) {  // a_i ~ 0: negligible, skip the 4KB row read
      float4 xv = *reinterpret_cast<const float4*>(x + (size_t)i * D + c);
      acc.x = fmaf(wm, xv.x, acc.x);
      acc.y = fmaf(wm, xv.y, acc.y);
      acc.z = fmaf(wm, xv.z, acc.z);
      acc.w = fmaf(wm, xv.w, acc.w);
    }
  }
  if (s1 < N) {  // first column of row r+1 crosses back into row r
    float wc = crossv[s1];
    if (wc >= 1e-7f) {
      float4 xv = *reinterpret_cast<const float4*>(x + (size_t)s1 * D + c);
      acc.x = fmaf(wc, xv.x, acc.x);
      acc.y = fmaf(wc, xv.y, acc.y);
      acc.z = fmaf(wc, xv.z, acc.z);
      acc.w = fmaf(wc, xv.w, acc.w);
    }
  }
  *reinterpret_cast<float4*>(out + (size_t)r * D + c) = acc;
}

extern "C" void kernel_launch(void* const* d_in, const int* in_sizes, int n_in,
                              void* d_out, int out_size, void* d_ws, size_t ws_size,
                              hipStream_t stream) {
  const float* x = (const float*)d_in[0];
  const float* w = (const float*)d_in[1];
  float* out = (float*)d_out;
  int D = in_sizes[1];      // 1024
  int N = in_sizes[0] / D;  // 8192

  float* a = (float*)d_ws;
  float* mainv = a + N;
  float* crossv = mainv + N;
  int* rowptr = (int*)(crossv + N);  // N+1 entries
  double* blocksum = (double*)(((uintptr_t)(rowptr + N + 1) + 15) & ~15ull);
  // blocksum: N/4 doubles, every slot written by k1 each call (poison-safe)

  hipLaunchKernelGGL(dot_sigmoid_kernel, dim3(N / 4), dim3(256), 0, stream,
                     x, w, a, blocksum, rowptr, N, D);
  hipLaunchKernelGGL(scan_emit_kernel, dim3(N / 256), dim3(256), 0, stream,
                     a, blocksum, mainv, crossv, rowptr, N);
  hipLaunchKernelGGL(out_kernel, dim3(N), dim3(256), 0, stream,
                     x, mainv, crossv, rowptr, out, N, D);
}